// Round 1
// baseline (683.443 us; speedup 1.0000x reference)
//
#include <hip/hip_runtime.h>

// Problem constants (fixed shapes from setup_inputs)
#define BATCH   8
#define DIM     8
#define NPIX    (1024 * 1024)
#define NCLS    5
#define SIGMA_V 0.5f
#define SIGMA_D 3.0f

#define PBLK 128   // blocks per sample
#define TPB  256   // threads per block

// ws layout: float ws[BATCH][NCLS][10]  -> per (b,c): [count, sumsq, sum[0..7]]
#define WS_FLOATS (BATCH * NCLS * 10)

__global__ void lanenet_init_ws(float* __restrict__ ws) {
    int t = blockIdx.x * blockDim.x + threadIdx.x;
    if (t < WS_FLOATS) ws[t] = 0.0f;
}

__device__ __forceinline__ float wave_sum(float v) {
    #pragma unroll
    for (int off = 32; off > 0; off >>= 1)
        v += __shfl_xor(v, off, 64);
    return v;
}

__global__ void lanenet_accum(const float* __restrict__ emb,
                              const int* __restrict__ seg,
                              float* __restrict__ ws) {
    const int b = blockIdx.y;
    const float* embB = emb + (size_t)b * DIM * NPIX;
    const int4* segB  = (const int4*)(seg + (size_t)b * NPIX);

    float cnt[NCLS];
    float sq[NCLS];
    float sm[NCLS][DIM];
    #pragma unroll
    for (int c = 0; c < NCLS; ++c) {
        cnt[c] = 0.0f; sq[c] = 0.0f;
        #pragma unroll
        for (int d = 0; d < DIM; ++d) sm[c][d] = 0.0f;
    }

    const int nG = NPIX / 4;               // float4 groups per sample
    const int stride = PBLK * TPB;

    for (int g = blockIdx.x * TPB + threadIdx.x; g < nG; g += stride) {
        int4 s4 = segB[g];
        float4 x[DIM];
        #pragma unroll
        for (int d = 0; d < DIM; ++d)
            x[d] = ((const float4*)(embB + (size_t)d * NPIX))[g];

        #pragma unroll
        for (int p = 0; p < 4; ++p) {
            const int s = (p == 0) ? s4.x : (p == 1) ? s4.y : (p == 2) ? s4.z : s4.w;
            float xv[DIM];
            #pragma unroll
            for (int d = 0; d < DIM; ++d)
                xv[d] = (p == 0) ? x[d].x : (p == 1) ? x[d].y : (p == 2) ? x[d].z : x[d].w;

            float n2 = 0.0f;
            #pragma unroll
            for (int d = 0; d < DIM; ++d) n2 = fmaf(xv[d], xv[d], n2);

            #pragma unroll
            for (int c = 0; c < NCLS; ++c) {
                const float sel = (s == c) ? 1.0f : 0.0f;
                cnt[c] += sel;
                sq[c]  = fmaf(sel, n2, sq[c]);
                #pragma unroll
                for (int d = 0; d < DIM; ++d)
                    sm[c][d] = fmaf(sel, xv[d], sm[c][d]);
            }
        }
    }

    // wave-level reduction + one set of global atomics per wave (lane 0)
    const bool leader = ((threadIdx.x & 63) == 0);
    float* wsb = ws + (size_t)b * NCLS * 10;
    #pragma unroll
    for (int c = 0; c < NCLS; ++c) {
        float v = wave_sum(cnt[c]);
        if (leader) atomicAdd(&wsb[c * 10 + 0], v);
        v = wave_sum(sq[c]);
        if (leader) atomicAdd(&wsb[c * 10 + 1], v);
        #pragma unroll
        for (int d = 0; d < DIM; ++d) {
            v = wave_sum(sm[c][d]);
            if (leader) atomicAdd(&wsb[c * 10 + 2 + d], v);
        }
    }
}

__global__ void lanenet_finalize(const float* __restrict__ ws,
                                 float* __restrict__ out) {
    __shared__ float lsamp[BATCH];
    const int t = threadIdx.x;
    if (t < BATCH) {
        const float* a = ws + (size_t)t * NCLS * 10;
        float m[NCLS][DIM];
        float var = 0.0f;
        #pragma unroll
        for (int c = 0; c < NCLS; ++c) {
            const float c0 = fmaxf(a[c * 10 + 0], 1.0f);
            const float qq = a[c * 10 + 1];
            float s2 = 0.0f;
            #pragma unroll
            for (int d = 0; d < DIM; ++d) {
                const float s = a[c * 10 + 2 + d];
                m[c][d] = s / c0;
                s2 = fmaf(s, s, s2);
            }
            float ss = qq - s2 / c0;
            ss = fmaxf(ss, 0.0f);
            var += fmaxf(sqrtf(ss) - SIGMA_V, 0.0f);
        }
        var *= (1.0f / NCLS);

        float dist = 0.0f;
        #pragma unroll
        for (int i = 0; i < NCLS; ++i) {
            #pragma unroll
            for (int j = i + 1; j < NCLS; ++j) {
                float d2 = 0.0f;
                #pragma unroll
                for (int d = 0; d < DIM; ++d) {
                    const float df = m[i][d] - m[j][d];
                    d2 = fmaf(df, df, d2);
                }
                dist += 2.0f * fmaxf(SIGMA_D - sqrtf(d2), 0.0f);
            }
        }
        dist *= (1.0f / (NCLS * (NCLS - 1)));

        lsamp[t] = var + dist;
    }
    __syncthreads();
    if (t == 0) {
        float s = 0.0f;
        #pragma unroll
        for (int b = 0; b < BATCH; ++b) s += lsamp[b];
        out[0] = s * (1.0f / BATCH);
    }
}

extern "C" void kernel_launch(void* const* d_in, const int* in_sizes, int n_in,
                              void* d_out, int out_size, void* d_ws, size_t ws_size,
                              hipStream_t stream) {
    (void)in_sizes; (void)n_in; (void)out_size; (void)ws_size;
    const float* emb = (const float*)d_in[0];
    const int*   seg = (const int*)d_in[1];
    float* out = (float*)d_out;
    float* ws  = (float*)d_ws;

    lanenet_init_ws<<<1, 512, 0, stream>>>(ws);
    dim3 grid(PBLK, BATCH);
    lanenet_accum<<<grid, TPB, 0, stream>>>(emb, seg, ws);
    lanenet_finalize<<<1, 64, 0, stream>>>(ws, out);
}

// Round 2
// 413.908 us; speedup vs baseline: 1.6512x; 1.6512x over previous
//
#include <hip/hip_runtime.h>

// Problem constants (fixed shapes from setup_inputs)
#define BATCH   8
#define DIM     8
#define NPIX    (1024 * 1024)
#define NCLS    5
#define SIGMA_V 0.5f
#define SIGMA_D 3.0f

#define PBLK 128   // blocks per sample
#define TPB  256   // threads per block
#define NWAVE (TPB / 64)

// ws layout: float ws[BATCH][NCLS][10]  -> per (b,c): [count, sumsq, sum[0..7]]
#define WS_FLOATS (BATCH * NCLS * 10)
#define ACC50 (NCLS * 10)

__global__ void lanenet_init_ws(float* __restrict__ ws) {
    int t = blockIdx.x * blockDim.x + threadIdx.x;
    if (t < WS_FLOATS) ws[t] = 0.0f;
}

__device__ __forceinline__ float wave_sum(float v) {
    #pragma unroll
    for (int off = 32; off > 0; off >>= 1)
        v += __shfl_xor(v, off, 64);
    return v;
}

// __launch_bounds__(256, 4): min 4 waves/EU -> VGPR cap 128. Without this the
// compiler capped at 64 VGPRs and spilled the 50 accumulators to scratch
// (R1: 440us with VALUBusy 4%, HBM 4%, duration independent of cache state).
__global__ __launch_bounds__(TPB, 4) void lanenet_accum(
        const float* __restrict__ emb,
        const int* __restrict__ seg,
        float* __restrict__ ws) {
    const int b = blockIdx.y;
    const float* embB = emb + (size_t)b * DIM * NPIX;
    const int4* segB  = (const int4*)(seg + (size_t)b * NPIX);

    float cnt[NCLS];
    float sq[NCLS];
    float sm[NCLS][DIM];
    #pragma unroll
    for (int c = 0; c < NCLS; ++c) {
        cnt[c] = 0.0f; sq[c] = 0.0f;
        #pragma unroll
        for (int d = 0; d < DIM; ++d) sm[c][d] = 0.0f;
    }

    const int nG = NPIX / 4;               // float4 groups per sample
    const int stride = PBLK * TPB;

    for (int g = blockIdx.x * TPB + threadIdx.x; g < nG; g += stride) {
        int4 s4 = segB[g];
        float4 x[DIM];
        #pragma unroll
        for (int d = 0; d < DIM; ++d)
            x[d] = ((const float4*)(embB + (size_t)d * NPIX))[g];

        #pragma unroll
        for (int p = 0; p < 4; ++p) {
            const int s = (p == 0) ? s4.x : (p == 1) ? s4.y : (p == 2) ? s4.z : s4.w;
            float xv[DIM];
            #pragma unroll
            for (int d = 0; d < DIM; ++d)
                xv[d] = (p == 0) ? x[d].x : (p == 1) ? x[d].y : (p == 2) ? x[d].z : x[d].w;

            float n2 = 0.0f;
            #pragma unroll
            for (int d = 0; d < DIM; ++d) n2 = fmaf(xv[d], xv[d], n2);

            #pragma unroll
            for (int c = 0; c < NCLS; ++c) {
                const float sel = (s == c) ? 1.0f : 0.0f;
                cnt[c] += sel;
                sq[c]  = fmaf(sel, n2, sq[c]);
                #pragma unroll
                for (int d = 0; d < DIM; ++d)
                    sm[c][d] = fmaf(sel, xv[d], sm[c][d]);
            }
        }
    }

    // wave-level shuffle reduction -> LDS -> one atomicAdd per accumulator
    // per BLOCK (50/block instead of 50/wave).
    __shared__ float red[NWAVE][ACC50];
    const int lane = threadIdx.x & 63;
    const int w = threadIdx.x >> 6;

    #pragma unroll
    for (int c = 0; c < NCLS; ++c) {
        float v = wave_sum(cnt[c]);
        if (lane == 0) red[w][c * 10 + 0] = v;
        v = wave_sum(sq[c]);
        if (lane == 0) red[w][c * 10 + 1] = v;
        #pragma unroll
        for (int d = 0; d < DIM; ++d) {
            v = wave_sum(sm[c][d]);
            if (lane == 0) red[w][c * 10 + 2 + d] = v;
        }
    }
    __syncthreads();

    if (threadIdx.x < ACC50) {
        float s = 0.0f;
        #pragma unroll
        for (int i = 0; i < NWAVE; ++i) s += red[i][threadIdx.x];
        atomicAdd(&ws[(size_t)b * ACC50 + threadIdx.x], s);
    }
}

__global__ void lanenet_finalize(const float* __restrict__ ws,
                                 float* __restrict__ out) {
    __shared__ float lsamp[BATCH];
    const int t = threadIdx.x;
    if (t < BATCH) {
        const float* a = ws + (size_t)t * ACC50;
        float m[NCLS][DIM];
        float var = 0.0f;
        #pragma unroll
        for (int c = 0; c < NCLS; ++c) {
            const float c0 = fmaxf(a[c * 10 + 0], 1.0f);
            const float qq = a[c * 10 + 1];
            float s2 = 0.0f;
            #pragma unroll
            for (int d = 0; d < DIM; ++d) {
                const float s = a[c * 10 + 2 + d];
                m[c][d] = s / c0;
                s2 = fmaf(s, s, s2);
            }
            float ss = qq - s2 / c0;
            ss = fmaxf(ss, 0.0f);
            var += fmaxf(sqrtf(ss) - SIGMA_V, 0.0f);
        }
        var *= (1.0f / NCLS);

        float dist = 0.0f;
        #pragma unroll
        for (int i = 0; i < NCLS; ++i) {
            #pragma unroll
            for (int j = i + 1; j < NCLS; ++j) {
                float d2 = 0.0f;
                #pragma unroll
                for (int d = 0; d < DIM; ++d) {
                    const float df = m[i][d] - m[j][d];
                    d2 = fmaf(df, df, d2);
                }
                dist += 2.0f * fmaxf(SIGMA_D - sqrtf(d2), 0.0f);
            }
        }
        dist *= (1.0f / (NCLS * (NCLS - 1)));

        lsamp[t] = var + dist;
    }
    __syncthreads();
    if (t == 0) {
        float s = 0.0f;
        #pragma unroll
        for (int b = 0; b < BATCH; ++b) s += lsamp[b];
        out[0] = s * (1.0f / BATCH);
    }
}

extern "C" void kernel_launch(void* const* d_in, const int* in_sizes, int n_in,
                              void* d_out, int out_size, void* d_ws, size_t ws_size,
                              hipStream_t stream) {
    (void)in_sizes; (void)n_in; (void)out_size; (void)ws_size;
    const float* emb = (const float*)d_in[0];
    const int*   seg = (const int*)d_in[1];
    float* out = (float*)d_out;
    float* ws  = (float*)d_ws;

    lanenet_init_ws<<<1, 512, 0, stream>>>(ws);
    dim3 grid(PBLK, BATCH);
    lanenet_accum<<<grid, TPB, 0, stream>>>(emb, seg, ws);
    lanenet_finalize<<<1, 64, 0, stream>>>(ws, out);
}